// Round 6
// baseline (519.156 us; speedup 1.0000x reference)
//
#include <hip/hip_runtime.h>
#include <math.h>

// B=4, L=4096, H=16, NB=64, D=1024, HID=128, NS=1024, TOKENS=16384
// Chunks: 64 tokens -> 64 chunks/seq, 256 chunks total.
// out layout: [theta_hat 16777216 | Pi 1024 | K 16777216 | R 16777216]
static constexpr size_t OUT_THETA = 0;
static constexpr size_t OUT_PI    = 16777216;
static constexpr size_t OUT_K     = 16778240;
static constexpr size_t OUT_R     = 33555456;

#define PI_F     3.14159265358979323846f
#define INV2PI_F 0.15915494309189535f
#define PI2_HI   6.28318548202514648f
#define PI2_LO  -1.7484556e-7f
#define SPLIT_S  2048.0f
#define SPLIT_IS (1.0f / 2048.0f)

typedef _Float16 half8 __attribute__((ext_vector_type(8)));
typedef float    f32x4 __attribute__((ext_vector_type(4)));

__device__ __forceinline__ float gelu_f(float x) {
    return 0.5f * x * (1.0f + erff(x * 0.70710678118654752f));
}

// fast transcendentals for the mm2 epilogue (error ~1e-6 abs, far below the
// 0.03125 absmax set by the f16-split GEMM; branchless, correct at +-inf/NaN)
__device__ __forceinline__ float exp_fast(float x) { return __expf(x); }
__device__ __forceinline__ float tanh_fast(float x) {
    float e = __expf(2.0f * x);                      // inf for large x -> 1
    return 1.0f - __fdividef(2.0f, e + 1.0f);        // 0 for large -x -> -1
}

// ---------------------------------------------------------------------------
// k_prep: transpose + f16-split the four weight matrices (131072 els each).
// ---------------------------------------------------------------------------
__global__ __launch_bounds__(256) void k_prep(
    const float* __restrict__ Wr1, const float* __restrict__ Wm1,
    const float* __restrict__ Wr2, const float* __restrict__ Wm2,
    _Float16* __restrict__ W1rT, _Float16* __restrict__ W1mTh, _Float16* __restrict__ W1mTl,
    _Float16* __restrict__ W2rT, _Float16* __restrict__ W2mTh, _Float16* __restrict__ W2mTl)
{
    const int i = blockIdx.x * 256 + threadIdx.x;     // 0..131071
    { // W1: i = k*128 + c
        const int k = i >> 7, c = i & 127;
        const int o = c * 1024 + k;
        W1rT[o] = (_Float16)Wr1[i];
        float w = Wm1[i];
        _Float16 h = (_Float16)w;
        W1mTh[o] = h;
        W1mTl[o] = (_Float16)((w - (float)h) * SPLIT_S);
    }
    { // W2: i = k*1024 + c
        const int k = i >> 10, c = i & 1023;
        const int o = c * 128 + k;
        W2rT[o] = (_Float16)Wr2[i];
        float w = Wm2[i];
        _Float16 h = (_Float16)w;
        W2mTh[o] = h;
        W2mTl[o] = (_Float16)((w - (float)h) * SPLIT_S);
    }
}

// ---------------------------------------------------------------------------
// k_mm1: BOTH heads in one pass: Hr = gelu(X@Wr1+br1), Hm = gelu(X@Wm1+bm1).
// REVERTED to the round-4-benched version (best total, 470us). The (256,1)
// 60KB double-buffer variant regressed: its single-barrier schedule forces a
// vmcnt(0) drain right after the short MFMA cluster, and 1 block/CU is
// grid-limited anyway. X register-direct (zero cross-wave reuse); W1 in LDS
// (8x reuse per stage); 2-phase prefetch.
// ---------------------------------------------------------------------------
__global__ __launch_bounds__(256, 3) void k_mm1(
    const float* __restrict__ X,
    const _Float16* __restrict__ WrT,
    const _Float16* __restrict__ WmTh, const _Float16* __restrict__ WmTl,
    const float* __restrict__ br1, const float* __restrict__ bm1,
    _Float16* __restrict__ OHr, _Float16* __restrict__ OHmh, _Float16* __restrict__ OHml)
{
    __shared__ _Float16 sm[15360];     // 30 KB
    _Float16* WR = sm;                 // [128][40]
    _Float16* WH = sm + 5120;
    _Float16* WL = sm + 10240;

    const int m0   = blockIdx.x * 64;
    const int tid  = threadIdx.x;
    const int lane = tid & 63;
    const int quad = lane >> 4, l15 = lane & 15;
    const int rt   = tid >> 6;                       // wave = row-tile

    f32x4 accR[8] = {};
    f32x4 accA[8] = {};
    f32x4 accB[8] = {};

    // per-lane X stream: row rt*16+l15, k-seg quad*8
    const float* xp = X + (size_t)(m0 + rt * 16 + l15) * 1024 + quad * 8;
    float4 xa = *(const float4*)(xp);
    float4 xb = *(const float4*)(xp + 4);

    // prologue: W tile for k0=0
    half8 wr[2], wh[2], wl[2];
#pragma unroll
    for (int it = 0; it < 2; ++it) {
        const int u = tid + it * 256;                // col 0..127, seg 0..3
        const int col = u >> 2, ws = u & 3;
        const size_t go = (size_t)col * 1024 + ws * 8;
        wr[it] = *(const half8*)(WrT  + go);
        wh[it] = *(const half8*)(WmTh + go);
        wl[it] = *(const half8*)(WmTl + go);
    }

    for (int k0 = 0; k0 < 1024; k0 += 32) {
        __syncthreads();                             // prev MFMA ds_reads done
#pragma unroll
        for (int it = 0; it < 2; ++it) {
            const int u = tid + it * 256;
            const int col = u >> 2, ws = u & 3;
            *(half8*)&WR[col * 40 + ws * 8] = wr[it];
            *(half8*)&WH[col * 40 + ws * 8] = wh[it];
            *(half8*)&WL[col * 40 + ws * 8] = wl[it];
        }
        __syncthreads();
        // split current X fragment in registers
        half8 ah, al;
#pragma unroll
        for (int c = 0; c < 8; ++c) {
            float v = (c < 4) ? ((const float*)&xa)[c] : ((const float*)&xb)[c - 4];
            _Float16 h = (_Float16)v;
            ah[c] = h;
            al[c] = (_Float16)((v - (float)h) * SPLIT_S);
        }
        // prefetch next k-step (latency hides under MFMAs + next barrier)
        if (k0 + 32 < 1024) {
            xa = *(const float4*)(xp + k0 + 32);
            xb = *(const float4*)(xp + k0 + 36);
#pragma unroll
            for (int it = 0; it < 2; ++it) {
                const int u = tid + it * 256;
                const int col = u >> 2, ws = u & 3;
                const size_t go = (size_t)col * 1024 + k0 + 32 + ws * 8;
                wr[it] = *(const half8*)(WrT  + go);
                wh[it] = *(const half8*)(WmTh + go);
                wl[it] = *(const half8*)(WmTl + go);
            }
        }
#pragma unroll
        for (int ct = 0; ct < 8; ++ct) {
            half8 bhr = *(const half8*)&WR[(ct * 16 + l15) * 40 + quad * 8];
            accR[ct] = __builtin_amdgcn_mfma_f32_16x16x32_f16(ah, bhr, accR[ct], 0, 0, 0);
            half8 bhm = *(const half8*)&WH[(ct * 16 + l15) * 40 + quad * 8];
            accA[ct] = __builtin_amdgcn_mfma_f32_16x16x32_f16(ah, bhm, accA[ct], 0, 0, 0);
            half8 blm = *(const half8*)&WL[(ct * 16 + l15) * 40 + quad * 8];
            accB[ct] = __builtin_amdgcn_mfma_f32_16x16x32_f16(ah, blm, accB[ct], 0, 0, 0);
            accB[ct] = __builtin_amdgcn_mfma_f32_16x16x32_f16(al, bhm, accB[ct], 0, 0, 0);
        }
    }
    // epilogue: bias + exact GELU; C/D layout col=lane&15, row=quad*4+reg
#pragma unroll
    for (int ct = 0; ct < 8; ++ct) {
        const int col = ct * 16 + l15;
        const float bR = br1[col];
        const float bM = bm1[col];
#pragma unroll
        for (int reg = 0; reg < 4; ++reg) {
            const int token = m0 + rt * 16 + quad * 4 + reg;
            const size_t o = (size_t)token * 128 + col;
            float gr = gelu_f(accR[ct][reg] + bR);
            OHr[o] = (_Float16)gr;
            float gm = gelu_f(accA[ct][reg] + accB[ct][reg] * SPLIT_IS + bM);
            _Float16 h = (_Float16)gm;
            OHmh[o] = h;
            OHml[o] = (_Float16)((gm - (float)h) * SPLIT_S);
        }
    }
}

// ---------------------------------------------------------------------------
// k_mm2: GEMM2 (both heads, K=128, MFMA) + elementwise tail + chunk aggregates.
// Round-6 changes (133us, occ 38.6%, latency-bound -> attack stalls):
//  * __launch_bounds__(256,5): 30KB LDS allows 5 blocks/CU (150KB), was
//    artificially capped at 4. VGPR budget 102 vs 56 used.
//  * theta batch-prefetch: all 16 loads issued into regs before the epilogue
//    math (was one load per fold iteration = serial latency).
//  * __expf / branchless exp-based tanh in the epilogue (TRANS-pipe chains
//    were ~18K cyc/SIMD); error ~1e-6 << 0.03125 absmax from the f16 split.
//  * dropped nontemporal R store (round-5 WRITE_SIZE grew +6MB beyond the
//    A16/U16 increment -> it was defeating write-combining).
// ---------------------------------------------------------------------------
__global__ __launch_bounds__(256, 5) void k_mm2(
    const _Float16* __restrict__ Hr, const _Float16* __restrict__ Hmh, const _Float16* __restrict__ Hml,
    const _Float16* __restrict__ W2rT, const _Float16* __restrict__ W2mTh, const _Float16* __restrict__ W2mTl,
    const float* __restrict__ br2, const float* __restrict__ bm2,
    const float* __restrict__ log_Pi, const float* __restrict__ theta,
    float* __restrict__ out, float* __restrict__ Aws, float* __restrict__ Uws,
    float* __restrict__ A16, float* __restrict__ U16)
{
    __shared__ _Float16 sm[15360];
    _Float16* AHr = sm;                // [64][40]
    _Float16* AHm = sm + 2560;
    _Float16* ALm = sm + 5120;
    _Float16* BHr = sm + 7680;         // [64][40]
    _Float16* BHm = sm + 10240;
    _Float16* BLm = sm + 12800;

    const int tt = blockIdx.x;         // chunk 0..255
    const int jt = blockIdx.y;         // 0..15
    const int m0 = tt * 64, n0 = jt * 64;
    const int tid  = threadIdx.x;
    const int lane = tid & 63;
    const int quad = lane >> 4, l15 = lane & 15;
    const int ct   = tid >> 6;                       // wave = col-tile
    const int row  = tid >> 2, seg = tid & 3;        // loaders

    f32x4 accr[4] = {};
    f32x4 accA[4] = {};
    f32x4 accB[4] = {};

    const size_t aobase = (size_t)(m0 + row) * 128 + seg * 8;
    const size_t bobase = (size_t)(n0 + row) * 128 + seg * 8;
    half8 la = *(const half8*)(Hr    + aobase);
    half8 lb = *(const half8*)(Hmh   + aobase);
    half8 lc = *(const half8*)(Hml   + aobase);
    half8 ld = *(const half8*)(W2rT  + bobase);
    half8 le = *(const half8*)(W2mTh + bobase);
    half8 lf = *(const half8*)(W2mTl + bobase);

    for (int k0 = 0; k0 < 128; k0 += 32) {
        __syncthreads();
        const int so = row * 40 + seg * 8;
        *(half8*)&AHr[so] = la;
        *(half8*)&AHm[so] = lb;
        *(half8*)&ALm[so] = lc;
        *(half8*)&BHr[so] = ld;
        *(half8*)&BHm[so] = le;
        *(half8*)&BLm[so] = lf;
        __syncthreads();
        if (k0 + 32 < 128) {                         // prefetch next k-step
            la = *(const half8*)(Hr    + aobase + k0 + 32);
            lb = *(const half8*)(Hmh   + aobase + k0 + 32);
            lc = *(const half8*)(Hml   + aobase + k0 + 32);
            ld = *(const half8*)(W2rT  + bobase + k0 + 32);
            le = *(const half8*)(W2mTh + bobase + k0 + 32);
            lf = *(const half8*)(W2mTl + bobase + k0 + 32);
        }
        const int bidx = (ct * 16 + l15) * 40 + quad * 8;
        half8 br_ = *(const half8*)&BHr[bidx];
        half8 bm_ = *(const half8*)&BHm[bidx];
        half8 bl_ = *(const half8*)&BLm[bidx];
#pragma unroll
        for (int rt = 0; rt < 4; ++rt) {
            const int aidx = (rt * 16 + l15) * 40 + quad * 8;
            half8 a_r = *(const half8*)&AHr[aidx];
            half8 a_h = *(const half8*)&AHm[aidx];
            half8 a_l = *(const half8*)&ALm[aidx];
            accr[rt] = __builtin_amdgcn_mfma_f32_16x16x32_f16(a_r, br_, accr[rt], 0, 0, 0);
            accA[rt] = __builtin_amdgcn_mfma_f32_16x16x32_f16(a_h, bm_, accA[rt], 0, 0, 0);
            accB[rt] = __builtin_amdgcn_mfma_f32_16x16x32_f16(a_h, bl_, accB[rt], 0, 0, 0);
            accB[rt] = __builtin_amdgcn_mfma_f32_16x16x32_f16(a_l, bm_, accB[rt], 0, 0, 0);
        }
    }

    const int col = n0 + ct * 16 + l15;              // one column per lane
    // batch-prefetch theta: 16 independent loads in flight before the math
    float th[4][4];
#pragma unroll
    for (int rt = 0; rt < 4; ++rt)
#pragma unroll
        for (int reg = 0; reg < 4; ++reg)
            th[rt][reg] = theta[(size_t)(m0 + rt * 16 + quad * 4 + reg) * 1024 + col];

    const float Pi_  = expf(log_Pi[col]);
    const float b2rv = br2[col];
    const float b2mv = bm2[col];
    float segA[4], segU[4];
#pragma unroll
    for (int rt = 0; rt < 4; ++rt) {
        float A = 1.0f, U = 0.0f;
#pragma unroll
        for (int reg = 0; reg < 4; ++reg) {
            const int token = m0 + rt * 16 + quad * 4 + reg;
            const size_t idx = (size_t)token * 1024 + col;
            float lr = fminf(fmaxf(accr[rt][reg] + b2rv, -5.0f), 5.0f);
            float R  = exp_fast(lr);
            float Kg = __fdividef(Pi_, fmaxf(Pi_ + R, 1e-8f));
            float zp = accA[rt][reg] + accB[rt][reg] * SPLIT_IS + b2mv;
            float z  = PI_F * tanh_fast(zp);
            float d  = z - th[rt][reg];
            float n  = rintf(d * INV2PI_F);
            float nu = fmaf(-n, PI2_HI, d);
            nu       = fmaf(-n, PI2_LO, nu);         // wrapped innovation
            float u  = Kg * nu;
            float al = 1.0f - Kg;
            U = fmaf(al, U, u);                      // token-ascending fold
            A *= al;
            out[OUT_K + idx]     = Kg;
            out[OUT_R + idx]     = R;
            out[OUT_THETA + idx] = u;                // u stashed in theta slot
        }
        segA[rt] = A; segU[rt] = U;
    }
    __syncthreads();                                 // MFMA LDS reads done; reuse
    float* cA = (float*)sm;                          // [64 cols][17 segs]
    float* cU = cA + 1088;
    const int colLocal = ct * 16 + l15;
#pragma unroll
    for (int rt = 0; rt < 4; ++rt) {
        cA[colLocal * 17 + rt * 4 + quad] = segA[rt];
        cU[colLocal * 17 + rt * 4 + quad] = segU[rt];
    }
    __syncthreads();
    if (tid < 64) {                                  // compose 16 segs in token order
        float A = 1.0f, U = 0.0f;
#pragma unroll
        for (int s = 0; s < 4; ++s) {
            float A4 = 1.0f, U4 = 0.0f;
#pragma unroll
            for (int q = 0; q < 4; ++q) {
                float a = cA[tid * 17 + s * 4 + q];
                float u = cU[tid * 17 + s * 4 + q];
                U4 = fmaf(a, U4, u);
                A4 *= a;
            }
            if (A16) {                               // 16-token segment aggregates
                A16[((size_t)tt * 4 + s) * 1024 + n0 + tid] = A4;
                U16[((size_t)tt * 4 + s) * 1024 + n0 + tid] = U4;
            }
            U = fmaf(A4, U, U4);
            A *= A4;
        }
        Aws[(size_t)tt * 1024 + n0 + tid] = A;
        Uws[(size_t)tt * 1024 + n0 + tid] = U;
    }
}

// ---------------------------------------------------------------------------
// K3: serial scan over 64 chunk aggregates per sequence -> chunk carries.
// float4-vectorized, unroll-8. grid 4 x 256 (thread owns 4 cols).
// ---------------------------------------------------------------------------
__global__ __launch_bounds__(256) void k_carry(
    const float* __restrict__ Aws, const float* __restrict__ Uws, float* __restrict__ Cws,
    const float* __restrict__ log_Pi, float* __restrict__ out)
{
    const int b  = blockIdx.x;                       // sequence 0..3
    const int j4 = threadIdx.x;                      // float4 col group
    if (b == 0) {
        float4 lp = *(const float4*)(log_Pi + j4 * 4);
        float4 p;
        p.x = expf(lp.x); p.y = expf(lp.y); p.z = expf(lp.z); p.w = expf(lp.w);
        *(float4*)(out + OUT_PI + j4 * 4) = p;
    }
    float4 carry = {0.0f, 0.0f, 0.0f, 0.0f};
#pragma unroll 8
    for (int c = 0; c < 64; ++c) {
        const size_t off = (size_t)(b * 64 + c) * 1024 + j4 * 4;
        float4 a = *(const float4*)(Aws + off);
        float4 u = *(const float4*)(Uws + off);
        *(float4*)(Cws + off) = carry;
        carry.x = fmaf(a.x, carry.x, u.x);
        carry.y = fmaf(a.y, carry.y, u.y);
        carry.z = fmaf(a.z, carry.z, u.z);
        carry.w = fmaf(a.w, carry.w, u.w);
    }
}

// ---------------------------------------------------------------------------
// K4a: apply at 16-token granularity (4096 waves = 4 waves/SIMD). Each wave
// (s = tid>>6, uniform) composes its in-chunk seg-prefix from A16/U16
// (<=3 affine folds), then scans 16 tokens. grid 1024 x 256.
// ---------------------------------------------------------------------------
__global__ __launch_bounds__(256) void k_apply16(
    const float* __restrict__ theta, const float* __restrict__ Cws,
    const float* __restrict__ A16, const float* __restrict__ U16,
    float* __restrict__ out)
{
    const int g   = blockIdx.x;                      // 0..1023
    const int tt  = g >> 2;                          // chunk 0..255
    const int cg  = g & 3;                           // col quarter
    const int tid = threadIdx.x;
    const int s   = tid >> 6;                        // seg in chunk (wave-uniform)
    const int j   = cg * 256 + (tid & 63) * 4;

    float4 d = *(const float4*)(Cws + (size_t)tt * 1024 + j);
    for (int ss = 0; ss < s; ++ss) {
        float4 a = *(const float4*)(A16 + ((size_t)tt * 4 + ss) * 1024 + j);
        float4 u = *(const float4*)(U16 + ((size_t)tt * 4 + ss) * 1024 + j);
        d.x = fmaf(a.x, d.x, u.x);
        d.y = fmaf(a.y, d.y, u.y);
        d.z = fmaf(a.z, d.z, u.z);
        d.w = fmaf(a.w, d.w, u.w);
    }
    size_t idx = (size_t)(tt * 64 + s * 16) * 1024 + j;
    const float* __restrict__ Kbase = out + OUT_K;
#pragma unroll 4
    for (int i = 0; i < 16; ++i) {
        float4 Kg = *(const float4*)(Kbase + idx);
        float4 u  = *(const float4*)(out + idx);
        float4 th = *(const float4*)(theta + idx);
        d.x = fmaf(1.0f - Kg.x, d.x, u.x);
        d.y = fmaf(1.0f - Kg.y, d.y, u.y);
        d.z = fmaf(1.0f - Kg.z, d.z, u.z);
        d.w = fmaf(1.0f - Kg.w, d.w, u.w);
        float4 r;
        r.x = th.x + d.x; r.y = th.y + d.y; r.z = th.z + d.z; r.w = th.w + d.w;
        *(float4*)(out + idx) = r;
        idx += 1024;
    }
}

// ---------------------------------------------------------------------------
// K4b: fallback 64-token apply (used if workspace too small for A16/U16).
// ---------------------------------------------------------------------------
__global__ __launch_bounds__(256) void k_apply(
    const float* __restrict__ theta, const float* __restrict__ Cws, float* __restrict__ out)
{
    const int bid = blockIdx.x;                      // c = bid&63, b = bid>>6
    const int c   = bid & 63;
    const int b   = bid >> 6;
    const int j0  = threadIdx.x * 4;
    float4 d = *(const float4*)(Cws + (size_t)(b * 64 + c) * 1024 + j0);
    size_t idx = (size_t)(b * 4096 + c * 64) * 1024 + j0;
    const float* __restrict__ Kbase = out + OUT_K;
#pragma unroll 4
    for (int i = 0; i < 64; ++i) {
        float4 Kg = *(const float4*)(Kbase + idx);
        float4 u  = *(const float4*)(out + idx);
        float4 th = *(const float4*)(theta + idx);
        d.x = fmaf(1.0f - Kg.x, d.x, u.x);
        d.y = fmaf(1.0f - Kg.y, d.y, u.y);
        d.z = fmaf(1.0f - Kg.z, d.z, u.z);
        d.w = fmaf(1.0f - Kg.w, d.w, u.w);
        float4 r;
        r.x = th.x + d.x; r.y = th.y + d.y; r.z = th.z + d.z; r.w = th.w + d.w;
        *(float4*)(out + idx) = r;
        idx += 1024;
    }
}

extern "C" void kernel_launch(void* const* d_in, const int* in_sizes, int n_in,
                              void* d_out, int out_size, void* d_ws, size_t ws_size,
                              hipStream_t stream)
{
    const float* theta = (const float*)d_in[0];
    const float* x     = (const float*)d_in[1];
    const float* logPi = (const float*)d_in[2];
    const float* Wr1   = (const float*)d_in[3];
    const float* br1   = (const float*)d_in[4];
    const float* Wr2   = (const float*)d_in[5];
    const float* br2   = (const float*)d_in[6];
    const float* Wm1   = (const float*)d_in[7];
    const float* bm1   = (const float*)d_in[8];
    const float* Wm2   = (const float*)d_in[9];
    const float* bm2   = (const float*)d_in[10];
    float* out = (float*)d_out;

    // workspace carve (halfs first, then floats) — ~25.7 MB with A16/U16
    _Float16* Hr    = (_Float16*)d_ws;                       // 16384*128
    _Float16* Hmh   = Hr  + (size_t)16384 * 128;
    _Float16* Hml   = Hmh + (size_t)16384 * 128;
    _Float16* W1rT  = Hml + (size_t)16384 * 128;             // 6 x 131072
    _Float16* W1mTh = W1rT  + 131072;
    _Float16* W1mTl = W1mTh + 131072;
    _Float16* W2rT  = W1mTl + 131072;
    _Float16* W2mTh = W2rT  + 131072;
    _Float16* W2mTl = W2mTh + 131072;
    float* Aws = (float*)(W2mTl + 131072);                   // 3 x 262144 f32
    float* Uws = Aws + 262144;
    float* Cws = Uws + 262144;
    float* A16 = Cws + 262144;                               // 2 x 1048576 f32
    float* U16 = A16 + 1048576;
    const size_t ws_need = (size_t)((char*)(U16 + 1048576) - (char*)d_ws);
    const bool seg16 = ws_size >= ws_need;

    k_prep<<<512, 256, 0, stream>>>(Wr1, Wm1, Wr2, Wm2,
                                    W1rT, W1mTh, W1mTl, W2rT, W2mTh, W2mTl);
    k_mm1<<<256, 256, 0, stream>>>(x, W1rT, W1mTh, W1mTl, br1, bm1, Hr, Hmh, Hml);
    k_mm2<<<dim3(256, 16), 256, 0, stream>>>(Hr, Hmh, Hml, W2rT, W2mTh, W2mTl,
                                             br2, bm2, logPi, theta, out, Aws, Uws,
                                             seg16 ? A16 : nullptr,
                                             seg16 ? U16 : nullptr);
    k_carry<<<4, 256, 0, stream>>>(Aws, Uws, Cws, logPi, out);
    if (seg16) {
        k_apply16<<<1024, 256, 0, stream>>>(theta, Cws, A16, U16, out);
    } else {
        k_apply<<<256, 256, 0, stream>>>(theta, Cws, out);
    }
}

// Round 7
// 435.534 us; speedup vs baseline: 1.1920x; 1.1920x over previous
//
#include <hip/hip_runtime.h>
#include <math.h>

// B=4, L=4096, H=16, NB=64, D=1024, HID=128, NS=1024, TOKENS=16384
// Chunks: 64 tokens -> 64 chunks/seq, 256 chunks total.
// out layout: [theta_hat 16777216 | Pi 1024 | K 16777216 | R 16777216]
static constexpr size_t OUT_THETA = 0;
static constexpr size_t OUT_PI    = 16777216;
static constexpr size_t OUT_K     = 16778240;
static constexpr size_t OUT_R     = 33555456;

#define PI_F     3.14159265358979323846f
#define INV2PI_F 0.15915494309189535f
#define PI2_HI   6.28318548202514648f
#define PI2_LO  -1.7484556e-7f
#define SPLIT_S  2048.0f
#define SPLIT_IS (1.0f / 2048.0f)

typedef _Float16 half8 __attribute__((ext_vector_type(8)));
typedef float    f32x4 __attribute__((ext_vector_type(4)));

__device__ __forceinline__ float gelu_f(float x) {
    return 0.5f * x * (1.0f + erff(x * 0.70710678118654752f));
}

// fast transcendentals for the mm2 epilogue: proven numerically safe in
// round 6 (absmax bit-identical 0.03125); branchless, correct at +-inf/NaN.
__device__ __forceinline__ float tanh_fast(float x) {
    float e = __expf(2.0f * x);                      // inf for large x -> 1
    return 1.0f - __fdividef(2.0f, e + 1.0f);        // 0 for large -x -> -1
}

// ---------------------------------------------------------------------------
// k_prep: transpose + f16-split the four weight matrices (131072 els each).
// ---------------------------------------------------------------------------
__global__ __launch_bounds__(256) void k_prep(
    const float* __restrict__ Wr1, const float* __restrict__ Wm1,
    const float* __restrict__ Wr2, const float* __restrict__ Wm2,
    _Float16* __restrict__ W1rT, _Float16* __restrict__ W1mTh, _Float16* __restrict__ W1mTl,
    _Float16* __restrict__ W2rT, _Float16* __restrict__ W2mTh, _Float16* __restrict__ W2mTl)
{
    const int i = blockIdx.x * 256 + threadIdx.x;     // 0..131071
    { // W1: i = k*128 + c
        const int k = i >> 7, c = i & 127;
        const int o = c * 1024 + k;
        W1rT[o] = (_Float16)Wr1[i];
        float w = Wm1[i];
        _Float16 h = (_Float16)w;
        W1mTh[o] = h;
        W1mTl[o] = (_Float16)((w - (float)h) * SPLIT_S);
    }
    { // W2: i = k*1024 + c
        const int k = i >> 10, c = i & 1023;
        const int o = c * 128 + k;
        W2rT[o] = (_Float16)Wr2[i];
        float w = Wm2[i];
        _Float16 h = (_Float16)w;
        W2mTh[o] = h;
        W2mTl[o] = (_Float16)((w - (float)h) * SPLIT_S);
    }
}

// ---------------------------------------------------------------------------
// k_mm1: BOTH heads in one pass (exact round-3 version, benched in the 470us
// total). X register-direct (zero cross-wave reuse); W1 in LDS (8x reuse per
// stage across the 4 waves); 2-phase prefetch; 30KB LDS; (256,3).
// ---------------------------------------------------------------------------
__global__ __launch_bounds__(256, 3) void k_mm1(
    const float* __restrict__ X,
    const _Float16* __restrict__ WrT,
    const _Float16* __restrict__ WmTh, const _Float16* __restrict__ WmTl,
    const float* __restrict__ br1, const float* __restrict__ bm1,
    _Float16* __restrict__ OHr, _Float16* __restrict__ OHmh, _Float16* __restrict__ OHml)
{
    __shared__ _Float16 sm[15360];     // 30 KB
    _Float16* WR = sm;                 // [128][40]
    _Float16* WH = sm + 5120;
    _Float16* WL = sm + 10240;

    const int m0   = blockIdx.x * 64;
    const int tid  = threadIdx.x;
    const int lane = tid & 63;
    const int quad = lane >> 4, l15 = lane & 15;
    const int rt   = tid >> 6;                       // wave = row-tile

    f32x4 accR[8] = {};
    f32x4 accA[8] = {};
    f32x4 accB[8] = {};

    const float* xp = X + (size_t)(m0 + rt * 16 + l15) * 1024 + quad * 8;
    float4 xa = *(const float4*)(xp);
    float4 xb = *(const float4*)(xp + 4);

    half8 wr[2], wh[2], wl[2];
#pragma unroll
    for (int it = 0; it < 2; ++it) {
        const int u = tid + it * 256;                // col 0..127, seg 0..3
        const int col = u >> 2, ws = u & 3;
        const size_t go = (size_t)col * 1024 + ws * 8;
        wr[it] = *(const half8*)(WrT  + go);
        wh[it] = *(const half8*)(WmTh + go);
        wl[it] = *(const half8*)(WmTl + go);
    }

    for (int k0 = 0; k0 < 1024; k0 += 32) {
        __syncthreads();                             // prev MFMA ds_reads done
#pragma unroll
        for (int it = 0; it < 2; ++it) {
            const int u = tid + it * 256;
            const int col = u >> 2, ws = u & 3;
            *(half8*)&WR[col * 40 + ws * 8] = wr[it];
            *(half8*)&WH[col * 40 + ws * 8] = wh[it];
            *(half8*)&WL[col * 40 + ws * 8] = wl[it];
        }
        __syncthreads();
        half8 ah, al;
#pragma unroll
        for (int c = 0; c < 8; ++c) {
            float v = (c < 4) ? ((const float*)&xa)[c] : ((const float*)&xb)[c - 4];
            _Float16 h = (_Float16)v;
            ah[c] = h;
            al[c] = (_Float16)((v - (float)h) * SPLIT_S);
        }
        if (k0 + 32 < 1024) {                        // prefetch next k-step
            xa = *(const float4*)(xp + k0 + 32);
            xb = *(const float4*)(xp + k0 + 36);
#pragma unroll
            for (int it = 0; it < 2; ++it) {
                const int u = tid + it * 256;
                const int col = u >> 2, ws = u & 3;
                const size_t go = (size_t)col * 1024 + k0 + 32 + ws * 8;
                wr[it] = *(const half8*)(WrT  + go);
                wh[it] = *(const half8*)(WmTh + go);
                wl[it] = *(const half8*)(WmTl + go);
            }
        }
#pragma unroll
        for (int ct = 0; ct < 8; ++ct) {
            half8 bhr = *(const half8*)&WR[(ct * 16 + l15) * 40 + quad * 8];
            accR[ct] = __builtin_amdgcn_mfma_f32_16x16x32_f16(ah, bhr, accR[ct], 0, 0, 0);
            half8 bhm = *(const half8*)&WH[(ct * 16 + l15) * 40 + quad * 8];
            accA[ct] = __builtin_amdgcn_mfma_f32_16x16x32_f16(ah, bhm, accA[ct], 0, 0, 0);
            half8 blm = *(const half8*)&WL[(ct * 16 + l15) * 40 + quad * 8];
            accB[ct] = __builtin_amdgcn_mfma_f32_16x16x32_f16(ah, blm, accB[ct], 0, 0, 0);
            accB[ct] = __builtin_amdgcn_mfma_f32_16x16x32_f16(al, bhm, accB[ct], 0, 0, 0);
        }
    }
#pragma unroll
    for (int ct = 0; ct < 8; ++ct) {
        const int col = ct * 16 + l15;
        const float bR = br1[col];
        const float bM = bm1[col];
#pragma unroll
        for (int reg = 0; reg < 4; ++reg) {
            const int token = m0 + rt * 16 + quad * 4 + reg;
            const size_t o = (size_t)token * 128 + col;
            float gr = gelu_f(accR[ct][reg] + bR);
            OHr[o] = (_Float16)gr;
            float gm = gelu_f(accA[ct][reg] + accB[ct][reg] * SPLIT_IS + bM);
            _Float16 h = (_Float16)gm;
            OHmh[o] = h;
            OHml[o] = (_Float16)((gm - (float)h) * SPLIT_S);
        }
    }
}

// ---------------------------------------------------------------------------
// k_mm2: GEMM2 + elementwise tail + chunk aggregates.
// K-loop: round-3 known-good (30KB, (256,4), 2-phase prefetch). Round-7
// change is the EPILOGUE MEMORY PATTERN only: previously every theta load and
// K/R/u store was a 4B scalar whose wave footprint was 4x 64B segments (wave
// spans just 16 cols) — 64 scattered VMEM instrs/thread. Now the dead GEMM
// LDS is reused as a 64x68-padded f32 tile:
//   theta: block-cooperative dense float4 loads (4 token-rows x 256B per
//          instr) -> LDS -> per-lane scalar reads (2-way bank alias = free).
//   u/K/R: scalar writes into the tile (acc layout), then dense float4
//          stores. 12 float4 stores replace 48 scalar stores per thread.
// Fast transcendentals kept (absmax bit-identical in round 6).
// ---------------------------------------------------------------------------
__global__ __launch_bounds__(256, 4) void k_mm2(
    const _Float16* __restrict__ Hr, const _Float16* __restrict__ Hmh, const _Float16* __restrict__ Hml,
    const _Float16* __restrict__ W2rT, const _Float16* __restrict__ W2mTh, const _Float16* __restrict__ W2mTl,
    const float* __restrict__ br2, const float* __restrict__ bm2,
    const float* __restrict__ log_Pi, const float* __restrict__ theta,
    float* __restrict__ out, float* __restrict__ Aws, float* __restrict__ Uws)
{
    __shared__ _Float16 sm[15360];
    _Float16* AHr = sm;                // [64][40]
    _Float16* AHm = sm + 2560;
    _Float16* ALm = sm + 5120;
    _Float16* BHr = sm + 7680;         // [64][40]
    _Float16* BHm = sm + 10240;
    _Float16* BLm = sm + 12800;

    const int tt = blockIdx.x;         // chunk 0..255
    const int jt = blockIdx.y;         // 0..15
    const int m0 = tt * 64, n0 = jt * 64;
    const int tid  = threadIdx.x;
    const int lane = tid & 63;
    const int quad = lane >> 4, l15 = lane & 15;
    const int ct   = tid >> 6;                       // wave = col-tile
    const int row  = tid >> 2, seg = tid & 3;        // loaders

    f32x4 accr[4] = {};
    f32x4 accA[4] = {};
    f32x4 accB[4] = {};

    const size_t aobase = (size_t)(m0 + row) * 128 + seg * 8;
    const size_t bobase = (size_t)(n0 + row) * 128 + seg * 8;
    half8 la = *(const half8*)(Hr    + aobase);
    half8 lb = *(const half8*)(Hmh   + aobase);
    half8 lc = *(const half8*)(Hml   + aobase);
    half8 ld = *(const half8*)(W2rT  + bobase);
    half8 le = *(const half8*)(W2mTh + bobase);
    half8 lf = *(const half8*)(W2mTl + bobase);

    for (int k0 = 0; k0 < 128; k0 += 32) {
        __syncthreads();
        const int so = row * 40 + seg * 8;
        *(half8*)&AHr[so] = la;
        *(half8*)&AHm[so] = lb;
        *(half8*)&ALm[so] = lc;
        *(half8*)&BHr[so] = ld;
        *(half8*)&BHm[so] = le;
        *(half8*)&BLm[so] = lf;
        __syncthreads();
        if (k0 + 32 < 128) {                         // prefetch next k-step
            la = *(const half8*)(Hr    + aobase + k0 + 32);
            lb = *(const half8*)(Hmh   + aobase + k0 + 32);
            lc = *(const half8*)(Hml   + aobase + k0 + 32);
            ld = *(const half8*)(W2rT  + bobase + k0 + 32);
            le = *(const half8*)(W2mTh + bobase + k0 + 32);
            lf = *(const half8*)(W2mTl + bobase + k0 + 32);
        }
        const int bidx = (ct * 16 + l15) * 40 + quad * 8;
        half8 br_ = *(const half8*)&BHr[bidx];
        half8 bm_ = *(const half8*)&BHm[bidx];
        half8 bl_ = *(const half8*)&BLm[bidx];
#pragma unroll
        for (int rt = 0; rt < 4; ++rt) {
            const int aidx = (rt * 16 + l15) * 40 + quad * 8;
            half8 a_r = *(const half8*)&AHr[aidx];
            half8 a_h = *(const half8*)&AHm[aidx];
            half8 a_l = *(const half8*)&ALm[aidx];
            accr[rt] = __builtin_amdgcn_mfma_f32_16x16x32_f16(a_r, br_, accr[rt], 0, 0, 0);
            accA[rt] = __builtin_amdgcn_mfma_f32_16x16x32_f16(a_h, bm_, accA[rt], 0, 0, 0);
            accB[rt] = __builtin_amdgcn_mfma_f32_16x16x32_f16(a_h, bl_, accB[rt], 0, 0, 0);
            accB[rt] = __builtin_amdgcn_mfma_f32_16x16x32_f16(a_l, bm_, accB[rt], 0, 0, 0);
        }
    }

    // ---- epilogue with LDS-tiled dense memory access ----
    float* tile = (float*)sm;          // 64 x 68 f32 = 17.4 KB (GEMM tiles dead)
    const int w    = tid >> 6;         // wave id
    const int trow = lane >> 4;        // token-in-group for coop ops
    const int cf   = (lane & 15) * 4;  // col offset for coop ops (float4)

    __syncthreads();                   // K-loop LDS reads complete
#pragma unroll
    for (int i = 0; i < 4; ++i) {      // stage theta: 4 dense rows / instr
        const int t = i * 16 + w * 4 + trow;
        *(float4*)&tile[t * 68 + cf] =
            *(const float4*)(theta + (size_t)(m0 + t) * 1024 + n0 + cf);
    }
    __syncthreads();

    const int col = n0 + ct * 16 + l15;              // one column per lane
    const float Pi_  = expf(log_Pi[col]);
    const float b2rv = br2[col];
    const float b2mv = bm2[col];
    float Rv[4][4], Kv[4][4], uv[4][4];
    float segA[4], segU[4];
#pragma unroll
    for (int rt = 0; rt < 4; ++rt) {
        float A = 1.0f, U = 0.0f;
#pragma unroll
        for (int reg = 0; reg < 4; ++reg) {
            const int tl = rt * 16 + quad * 4 + reg; // local token
            float lr = fminf(fmaxf(accr[rt][reg] + b2rv, -5.0f), 5.0f);
            float R  = __expf(lr);
            float Kg = __fdividef(Pi_, fmaxf(Pi_ + R, 1e-8f));
            float zp = accA[rt][reg] + accB[rt][reg] * SPLIT_IS + b2mv;
            float z  = PI_F * tanh_fast(zp);
            float d  = z - tile[tl * 68 + ct * 16 + l15];
            float n  = rintf(d * INV2PI_F);
            float nu = fmaf(-n, PI2_HI, d);
            nu       = fmaf(-n, PI2_LO, nu);         // wrapped innovation
            float u  = Kg * nu;
            float al = 1.0f - Kg;
            U = fmaf(al, U, u);                      // token-ascending fold
            A *= al;
            Rv[rt][reg] = R; Kv[rt][reg] = Kg; uv[rt][reg] = u;
        }
        segA[rt] = A; segU[rt] = U;
    }
    // three streams: scalar-write acc layout -> dense float4 store
#pragma unroll
    for (int s = 0; s < 3; ++s) {
        __syncthreads();               // prev phase tile reads done
#pragma unroll
        for (int rt = 0; rt < 4; ++rt)
#pragma unroll
            for (int reg = 0; reg < 4; ++reg) {
                const int tl = rt * 16 + quad * 4 + reg;
                float v = (s == 0) ? uv[rt][reg] : (s == 1) ? Kv[rt][reg] : Rv[rt][reg];
                tile[tl * 68 + ct * 16 + l15] = v;
            }
        __syncthreads();
        const size_t base = (s == 0) ? OUT_THETA : (s == 1) ? OUT_K : OUT_R;
#pragma unroll
        for (int i = 0; i < 4; ++i) {
            const int t = i * 16 + w * 4 + trow;
            *(float4*)(out + base + (size_t)(m0 + t) * 1024 + n0 + cf) =
                *(const float4*)&tile[t * 68 + cf];
        }
    }

    __syncthreads();                                 // tile reads done; reuse
    float* cA = (float*)sm;                          // [64 cols][17 segs]
    float* cU = cA + 1088;
    const int colLocal = ct * 16 + l15;
#pragma unroll
    for (int rt = 0; rt < 4; ++rt) {
        cA[colLocal * 17 + rt * 4 + quad] = segA[rt];
        cU[colLocal * 17 + rt * 4 + quad] = segU[rt];
    }
    __syncthreads();
    if (tid < 64) {                                  // compose 16 segs in token order
        float A = 1.0f, U = 0.0f;
#pragma unroll
        for (int s = 0; s < 16; ++s) {
            float a = cA[tid * 17 + s];
            float u = cU[tid * 17 + s];
            U = fmaf(a, U, u);
            A *= a;
        }
        Aws[(size_t)tt * 1024 + n0 + tid] = A;
        Uws[(size_t)tt * 1024 + n0 + tid] = U;
    }
}

// ---------------------------------------------------------------------------
// K3: serial scan over 64 chunk aggregates per sequence -> chunk carries.
// float4-vectorized, unroll-8. grid 4 x 256 (thread owns 4 cols).
// ---------------------------------------------------------------------------
__global__ __launch_bounds__(256) void k_carry(
    const float* __restrict__ Aws, const float* __restrict__ Uws, float* __restrict__ Cws,
    const float* __restrict__ log_Pi, float* __restrict__ out)
{
    const int b  = blockIdx.x;                       // sequence 0..3
    const int j4 = threadIdx.x;                      // float4 col group
    if (b == 0) {
        float4 lp = *(const float4*)(log_Pi + j4 * 4);
        float4 p;
        p.x = expf(lp.x); p.y = expf(lp.y); p.z = expf(lp.z); p.w = expf(lp.w);
        *(float4*)(out + OUT_PI + j4 * 4) = p;
    }
    float4 carry = {0.0f, 0.0f, 0.0f, 0.0f};
#pragma unroll 8
    for (int c = 0; c < 64; ++c) {
        const size_t off = (size_t)(b * 64 + c) * 1024 + j4 * 4;
        float4 a = *(const float4*)(Aws + off);
        float4 u = *(const float4*)(Uws + off);
        *(float4*)(Cws + off) = carry;
        carry.x = fmaf(a.x, carry.x, u.x);
        carry.y = fmaf(a.y, carry.y, u.y);
        carry.z = fmaf(a.z, carry.z, u.z);
        carry.w = fmaf(a.w, carry.w, u.w);
    }
}

// ---------------------------------------------------------------------------
// K4: apply — rescan each 64-token chunk seeded with its carry (round-3
// version, benched in the 470us total). grid 256 x 256, float4.
// ---------------------------------------------------------------------------
__global__ __launch_bounds__(256) void k_apply(
    const float* __restrict__ theta, const float* __restrict__ Cws, float* __restrict__ out)
{
    const int bid = blockIdx.x;                      // c = bid&63, b = bid>>6
    const int c   = bid & 63;
    const int b   = bid >> 6;
    const int j0  = threadIdx.x * 4;
    float4 d = *(const float4*)(Cws + (size_t)(b * 64 + c) * 1024 + j0);
    size_t idx = (size_t)(b * 4096 + c * 64) * 1024 + j0;
    const float* __restrict__ Kbase = out + OUT_K;
#pragma unroll 4
    for (int i = 0; i < 64; ++i) {
        float4 Kg = *(const float4*)(Kbase + idx);
        float4 u  = *(const float4*)(out + idx);
        float4 th = *(const float4*)(theta + idx);
        d.x = fmaf(1.0f - Kg.x, d.x, u.x);
        d.y = fmaf(1.0f - Kg.y, d.y, u.y);
        d.z = fmaf(1.0f - Kg.z, d.z, u.z);
        d.w = fmaf(1.0f - Kg.w, d.w, u.w);
        float4 r;
        r.x = th.x + d.x; r.y = th.y + d.y; r.z = th.z + d.z; r.w = th.w + d.w;
        *(float4*)(out + idx) = r;
        idx += 1024;
    }
}

extern "C" void kernel_launch(void* const* d_in, const int* in_sizes, int n_in,
                              void* d_out, int out_size, void* d_ws, size_t ws_size,
                              hipStream_t stream)
{
    const float* theta = (const float*)d_in[0];
    const float* x     = (const float*)d_in[1];
    const float* logPi = (const float*)d_in[2];
    const float* Wr1   = (const float*)d_in[3];
    const float* br1   = (const float*)d_in[4];
    const float* Wr2   = (const float*)d_in[5];
    const float* br2   = (const float*)d_in[6];
    const float* Wm1   = (const float*)d_in[7];
    const float* bm1   = (const float*)d_in[8];
    const float* Wm2   = (const float*)d_in[9];
    const float* bm2   = (const float*)d_in[10];
    float* out = (float*)d_out;

    // workspace carve (halfs first, then floats) — ~16.5 MB total
    _Float16* Hr    = (_Float16*)d_ws;                       // 16384*128
    _Float16* Hmh   = Hr  + (size_t)16384 * 128;
    _Float16* Hml   = Hmh + (size_t)16384 * 128;
    _Float16* W1rT  = Hml + (size_t)16384 * 128;             // 6 x 131072
    _Float16* W1mTh = W1rT  + 131072;
    _Float16* W1mTl = W1mTh + 131072;
    _Float16* W2rT  = W1mTl + 131072;
    _Float16* W2mTh = W2rT  + 131072;
    _Float16* W2mTl = W2mTh + 131072;
    float* Aws = (float*)(W2mTl + 131072);                   // 3 x 262144 f32
    float* Uws = Aws + 262144;
    float* Cws = Uws + 262144;

    k_prep<<<512, 256, 0, stream>>>(Wr1, Wm1, Wr2, Wm2,
                                    W1rT, W1mTh, W1mTl, W2rT, W2mTh, W2mTl);
    k_mm1<<<256, 256, 0, stream>>>(x, W1rT, W1mTh, W1mTl, br1, bm1, Hr, Hmh, Hml);
    k_mm2<<<dim3(256, 16), 256, 0, stream>>>(Hr, Hmh, Hml, W2rT, W2mTh, W2mTl,
                                             br2, bm2, logPi, theta, out, Aws, Uws);
    k_carry<<<4, 256, 0, stream>>>(Aws, Uws, Cws, logPi, out);
    k_apply<<<256, 256, 0, stream>>>(theta, Cws, out);
}